// Round 17
// baseline (429.772 us; speedup 1.0000x reference)
//
#include <hip/hip_runtime.h>
#include <hip/hip_fp16.h>
#include <math.h>

typedef _Float16 half8  __attribute__((ext_vector_type(8)));
typedef _Float16 half4v __attribute__((ext_vector_type(4)));
typedef __fp16   fp16x2v __attribute__((ext_vector_type(2)));
typedef float    f32x4  __attribute__((ext_vector_type(4)));

#define MFMA_F16 __builtin_amdgcn_mfma_f32_16x16x32_f16

namespace {

constexpr int M_ROWS = 64;                   // rows per block (4 waves x 64x64 tile)
// XOR-swizzled packed layouts (granule = 8 halves = 16 B):
//   Haddr(m,n) = m*256 + (((n>>3) ^ (m&7))<<3) + (n&7)     H: 32 KB (single)
//   Paddr(m,k) = PE_OFF + m*64 + (((k>>3) ^ (m&7))<<3) + (k&7) PE: 8 KB
// R16 proved 3 blocks/CU (45.5 KB LDS, (256,3)) is worth ~9%: pipes stop
// summing when each SIMD has 3 wave streams. R16 sat at the 170-reg cap and
// spilled ~2 dwords/thread/layer (WRITE_SIZE 77 MB). R17 cuts ~17 regs:
// B single-buffer JIT (LDS latency is covered by 3-wave TLP; the global
// A-loads keep their dist-1 ping-pong) + sigma stored to global immediately.
constexpr int H_OFF    = 0;                  // 16384 halves
constexpr int PE_OFF   = 16384;              // 4096 halves
constexpr int BIAS_OFF = 20480;              // 9*256 = 2304 halves
constexpr int LDS_HALVES = 22784;            // 45568 B -> 3 blocks/CU
constexpr size_t LDS_BYTES = (size_t)LDS_HALVES * sizeof(_Float16);

// Layer order: g1_0..g1_4, g2_0..g2_2, c_0, c_1, sig
constexpr int OFF_A[11] = {0,16384,81920,147456,212992,278528,360448,425984,491520,573440,577536};
constexpr int TOTAL_W   = 581632;   // fp16 elements in swizzled blob

struct Ptr11 { const float* p[11]; };

// Partial barrier: drain LDS only; register-targeted global loads stay in
// flight (consumers get per-use vmcnt waits from the compiler).
__device__ __forceinline__ void lds_barrier() {
  asm volatile("s_waitcnt lgkmcnt(0)\n\ts_barrier" ::: "memory");
}

// ---------------------------------------------------------------------------
// Weight pre-swizzle (R15): lane-fastest order -> coalesced reads. Blob:
//   256-out layers: blob[((kc*16 + nt)*64 + lane)*8 + j]
//   heads (L=9,10): blob[(kc*64 + lane)*8 + j]
//   element = W[remap(kc*32 + (lane>>4)*8 + j)][nt*16 + (lane&15)], 0 if pad.
// ---------------------------------------------------------------------------
__global__ void prep_kernel(Ptr11 wp, _Float16* __restrict__ ws) {
  int tid = blockIdx.x * blockDim.x + threadIdx.x;
  if (tid >= TOTAL_W) return;
  int L = 0;
#pragma unroll
  for (int i = 1; i < 11; ++i) if (tid >= OFF_A[i]) L = i;
  int e    = tid - OFF_A[L];
  int l15  = e & 15;           // fastest: n&15 -> coalesced W reads
  int j    = (e >> 4) & 7;
  int khi  = (e >> 7) & 3;
  int rest = e >> 9;
  int kc, nt;
  if (L <= 8) { nt = rest & 15; kc = rest >> 4; }
  else        { nt = 0;         kc = rest;      }
  int lane = khi * 16 + l15;
  int n    = nt * 16 + l15;
  int kpad = kc * 32 + khi * 8 + j;
  int k;
  if      (L == 0) k = (kpad < 63) ? kpad : -1;                               // g1_0: din 63 pad->64
  else if (L == 5) k = (kpad < 64) ? ((kpad < 63) ? kpad : -1) : kpad - 1;    // g2_0: [pe_x 63|f1 256]
  else if (L == 8) k = (kpad < 64) ? ((kpad < 39) ? kpad : -1) : kpad - 25;   // c_0:  [pe_d 39|f2 256]
  else             k = kpad;                                                  // din 256 exact
  int dout = (L == 9) ? 3 : ((L == 10) ? 1 : 256);
  float v = 0.f;
  if (k >= 0 && n < dout) v = wp.p[L][k * dout + n];
  int idx = (L <= 8) ? OFF_A[L] + ((kc * 16 + nt) * 64 + lane) * 8 + j
                     : OFF_A[L] + (kc * 64 + lane) * 8 + j;
  ws[idx] = (_Float16)v;
}

// ---------------------------------------------------------------------------
// One 256-out linear layer; wave cg computes rows [0,64) x cols [cg*64,+64).
// Single H buffer: lgkm-barrier after K-loop (reads done) and after epilogue
// (writes visible). Bias pre-loaded into acc. A: dist-1 ping-pong (aE/aO,
// aE caller-owned for cross-layer prefetch). B: single-buffer JIT (R17 —
// saves 16 regs; LDS latency covered by 3-wave TLP). Dual-base swizzle SR.
// ---------------------------------------------------------------------------
template <int PE_CH, int H_CH, bool RELU>
__device__ __forceinline__ void do_layer(_Float16* lds,
                                         const _Float16* __restrict__ blob,
                                         const _Float16* __restrict__ nblob,
                                         int bias_idx, int cg, int lane,
                                         half8 aE[4]) {
  constexpr int KCH = PE_CH + H_CH;   // even (2, 8, or 10)
  const int l15  = lane & 15;
  const int quad = lane >> 4;
  const int s7   = l15 & 7;          // swizzle key (row&7 == l15&7)
  const int c1   = s7 >> 2;          // chunk-granule xor bit
  const int q3   = (quad ^ (s7 & 3));

  // Bias -> acc init (kills the epilogue add; dead during the K-loop).
  f32x4 acc[4][4];
  {
    const _Float16* bb_ = lds + BIAS_OFF + bias_idx * 256 + cg * 64 + quad * 4;
#pragma unroll
    for (int nt = 0; nt < 4; ++nt) {
      half4v bh = *(const half4v*)(bb_ + nt * 16);
      f32x4 bf = { (float)bh[0], (float)bh[1], (float)bh[2], (float)bh[3] };
#pragma unroll
      for (int mt = 0; mt < 4; ++mt) acc[mt][nt] = bf;
    }
  }

  half8 aO[4], b[4];

  const _Float16* ap  = blob  + ((size_t)(cg * 256 + lane)) * 8;
  const _Float16* nap = nblob + ((size_t)(cg * 256 + lane)) * 8;
  const _Float16* pebase = lds + PE_OFF + l15 * 64 + q3 * 8;
  const _Float16* hbase  = lds + H_OFF + l15 * 256 + q3 * 8;
  const int co = c1 << 5;            // 32-half parity correction
  const _Float16* peE = pebase + co;
  const _Float16* peO = pebase - co;
  const _Float16* hbE = hbase + co;
  const _Float16* hbO = hbase - co;

#define LOADA(dst, base, KCG)                                                 \
  {                                                                           \
    const _Float16* apk = (base) + (size_t)(KCG) * 8192;                      \
    _Pragma("unroll") for (int nt = 0; nt < 4; ++nt)                          \
        dst[nt] = *(const half8*)(apk + nt * 512);                            \
  }

#define LOADB(KCG)                                                            \
  {                                                                           \
    if ((KCG) < PE_CH) {                                                      \
      const _Float16* bpp = (((KCG) & 1) ? peO : peE) + (KCG) * 32;           \
      _Pragma("unroll") for (int mt = 0; mt < 4; ++mt)                        \
          b[mt] = *(const half8*)(bpp + mt * 1024);                           \
    } else {                                                                  \
      const int U = (KCG) - PE_CH;                                            \
      const _Float16* bpp = ((U & 1) ? hbO : hbE) + U * 32;                   \
      _Pragma("unroll") for (int mt = 0; mt < 4; ++mt)                        \
          b[mt] = *(const half8*)(bpp + mt * 4096);                           \
    }                                                                         \
  }

#define DO_MFMA(ab)                                                           \
  {                                                                           \
    _Pragma("unroll") for (int mt = 0; mt < 4; ++mt)                          \
        _Pragma("unroll") for (int nt = 0; nt < 4; ++nt)                      \
            acc[mt][nt] = MFMA_F16(ab[nt], b[mt], acc[mt][nt], 0, 0, 0);      \
  }

#pragma unroll
  for (int kk = 0; kk < KCH; kk += 2) {
    LOADA(aO, ap, kk + 1)
    LOADB(kk)
    DO_MFMA(aE)                      // chunk kk
    if (kk + 2 < KCH) {
      LOADA(aE, ap, kk + 2)
    } else {
      LOADA(aE, nap, 0)              // cross-layer prefetch: next chunk 0
    }
    LOADB(kk + 1)
    DO_MFMA(aO)                      // chunk kk+1
  }
#undef LOADA
#undef LOADB
#undef DO_MFMA

  lds_barrier();   // all waves done READING H/PE before anyone overwrites H

  // Epilogue, SR: wa = mt*4096 + l15*256 + cg*64 + ((nt*2|qb)^s7)*8 + q1*4
  const int qb = quad >> 1, q1 = quad & 1;
  _Float16* wbase = lds + H_OFF + l15 * 256 + cg * 64 + q1 * 4;
  _Float16* wps[4] = { wbase + (((0 | qb) ^ s7) << 3),
                       wbase + (((2 | qb) ^ s7) << 3),
                       wbase + (((4 | qb) ^ s7) << 3),
                       wbase + (((6 | qb) ^ s7) << 3) };
#pragma unroll
  for (int mt = 0; mt < 4; ++mt) {
#pragma unroll
    for (int nt = 0; nt < 4; ++nt) {
      f32x4 v = acc[mt][nt];
      if (RELU) {
        v.x = fmaxf(v.x, 0.f); v.y = fmaxf(v.y, 0.f);
        v.z = fmaxf(v.z, 0.f); v.w = fmaxf(v.w, 0.f);
      }
      fp16x2v lo = __builtin_amdgcn_cvt_pkrtz(v.x, v.y);
      fp16x2v hi = __builtin_amdgcn_cvt_pkrtz(v.z, v.w);
      uint2 pk = { __builtin_bit_cast(unsigned int, lo),
                   __builtin_bit_cast(unsigned int, hi) };
      *(uint2*)(wps[nt] + mt * 4096) = pk;
    }
  }
  lds_barrier();   // writes visible to all waves
}

// Head (sig / c_1): NT=1 blob, K=256 over H; wave w rows [w*16,+16).
__device__ __forceinline__ f32x4 head_mt(const _Float16* lds,
                                         const _Float16* __restrict__ blob,
                                         int w, int lane) {
  const int l15  = lane & 15;
  const int quad = lane >> 4;
  const int s7   = l15 & 7;
  const int c1   = s7 >> 2;
  const int q3   = (quad ^ (s7 & 3));
  const _Float16* hb = lds + H_OFF + (w * 16 + l15) * 256 + q3 * 8;
  f32x4 res = (f32x4)0.f;
#pragma unroll
  for (int kc = 0; kc < 8; ++kc) {
    half8 a = *(const half8*)(blob + (kc * 64 + lane) * 8);
    half8 b = *(const half8*)(hb + ((kc ^ c1) << 5));
    res = MFMA_F16(a, b, res, 0, 0, 0);
  }
  return res;
}

// Positional encoding: f = tid&63 loop-invariant -> classify once per thread.
__device__ __forceinline__ void pe_pass(_Float16* lds, const float* __restrict__ src,
                                        int row0, int tid, int nfeat) {
  const int f  = tid & 63;
  const int rb = tid >> 6;
  const int fg = f >> 3, f7 = f & 7;
  int mode, c = 0, use_cos = 0;
  float freq = 0.f;
  if (f < 3) { mode = 0; c = f; }
  else if (f < nfeat) {
    int g = f - 3, li = g / 6, rem = g - li * 6;
    use_cos = (rem >= 3); c = use_cos ? rem - 3 : rem;
    freq = (float)(1 << li); mode = 1;
  } else mode = 2;
#pragma unroll
  for (int t = 0; t < 16; ++t) {
    int r = rb + t * 4;
    float v = 0.f;
    if (mode == 0) v = src[(row0 + r) * 3 + c];
    else if (mode == 1) {
      float a = src[(row0 + r) * 3 + c] * freq;
      v = use_cos ? __cosf(a) : __sinf(a);
    }
    lds[PE_OFF + r * 64 + (((fg ^ (r & 7)) << 3) | f7)] = (_Float16)v;
  }
}

__global__ __launch_bounds__(256, 3) void nerf_kernel(
    const _Float16* __restrict__ ws, const float* __restrict__ x,
    const float* __restrict__ dirp, Ptr11 bp, float* __restrict__ out) {
  extern __shared__ _Float16 lds[];
  const int tid  = threadIdx.x;
  const int lane = tid & 63;
  const int w    = tid >> 6;       // wave 0..3 (= col-group cg)
  const int l15  = lane & 15;
  const int quad = lane >> 4;
  const int row0 = blockIdx.x * M_ROWS;

  // ---- prefetch g1_0 chunk-0 A-frags (hide L2 behind pe_pass) ----
  half8 aE[4];
  {
    const _Float16* apk = ws + ((size_t)(w * 256 + lane)) * 8;
#pragma unroll
    for (int nt = 0; nt < 4; ++nt) aE[nt] = *(const half8*)(apk + nt * 512);
  }

  // ---- pe_x -> PE buffer; biases -> LDS (f16, once) ----
  pe_pass(lds, x, row0, tid, 63);
#pragma unroll
  for (int L = 0; L < 9; ++L)
    lds[BIAS_OFF + L * 256 + tid] = (_Float16)bp.p[L][tid];
  lds_barrier();

  // ---- G1: 63->256, 256->256 x4 (ReLU on all but last) ----
  do_layer<2, 0, true >(lds, ws + OFF_A[0], ws + OFF_A[1], 0, w, lane, aE);
  do_layer<0, 8, true >(lds, ws + OFF_A[1], ws + OFF_A[2], 1, w, lane, aE);
  do_layer<0, 8, true >(lds, ws + OFF_A[2], ws + OFF_A[3], 2, w, lane, aE);
  do_layer<0, 8, true >(lds, ws + OFF_A[3], ws + OFF_A[4], 3, w, lane, aE);
  do_layer<0, 8, false>(lds, ws + OFF_A[4], ws + OFF_A[5], 4, w, lane, aE);  // f1
  // ---- G2: [pe_x|f1] -> 256, 256->256, 256->256 (no ReLU on last) ----
  do_layer<2, 8, true >(lds, ws + OFF_A[5], ws + OFF_A[6], 5, w, lane, aE);  // pe_x last use
  do_layer<0, 8, true >(lds, ws + OFF_A[6], ws + OFF_A[7], 6, w, lane, aE);
  do_layer<0, 8, false>(lds, ws + OFF_A[7], ws + OFF_A[8], 7, w, lane, aE);  // f2

  // ---- sigma head reads f2; store to global IMMEDIATELY (R17: frees the
  // head state across c_0 — R16's residual spill site) ----
  {
    f32x4 sa = head_mt(lds, ws + OFF_A[10], w, lane);
    if (quad == 0)
      out[(size_t)(row0 + w * 16 + l15) * 4 + 3] = sa[0] + bp.p[10][0];
  }

  // ---- pe_d overwrites PE (pe_x dead) ----
  pe_pass(lds, dirp, row0, tid, 39);
  lds_barrier();     // pe_d visible before c_0; sig H-reads done

  // ---- color: c_0 [pe_d|f2] -> H (ReLU), c_1 reads H ----
  do_layer<2, 8, true>(lds, ws + OFF_A[8], ws, 8, w, lane, aE);
  f32x4 ca = head_mt(lds, ws + OFF_A[9], w, lane);
  if (quad == 0) {
    size_t i0 = (size_t)(row0 + w * 16 + l15) * 4;
    out[i0 + 0] = ca[0] + bp.p[9][0];
    out[i0 + 1] = ca[1] + bp.p[9][1];
    out[i0 + 2] = ca[2] + bp.p[9][2];
  }
}

}  // namespace

extern "C" void kernel_launch(void* const* d_in, const int* in_sizes, int n_in,
                              void* d_out, int out_size, void* d_ws, size_t ws_size,
                              hipStream_t stream) {
  const float* x   = (const float*)d_in[0];
  const float* dir = (const float*)d_in[1];
  Ptr11 wp, bp;
  for (int i = 0; i < 11; ++i) {
    wp.p[i] = (const float*)d_in[2 + 2 * i];
    bp.p[i] = (const float*)d_in[3 + 2 * i];
  }
  _Float16* ws = (_Float16*)d_ws;
  float* out = (float*)d_out;

  (void)hipFuncSetAttribute((const void*)nerf_kernel,
                            hipFuncAttributeMaxDynamicSharedMemorySize,
                            (int)LDS_BYTES);

  prep_kernel<<<(TOTAL_W + 255) / 256, 256, 0, stream>>>(wp, ws);
  nerf_kernel<<<262144 / M_ROWS, 256, LDS_BYTES, stream>>>(ws, x, dir, bp, out);
}

// Round 18
// 386.166 us; speedup vs baseline: 1.1129x; 1.1129x over previous
//
#include <hip/hip_runtime.h>
#include <hip/hip_fp16.h>
#include <math.h>

typedef _Float16 half8  __attribute__((ext_vector_type(8)));
typedef _Float16 half4v __attribute__((ext_vector_type(4)));
typedef __fp16   fp16x2v __attribute__((ext_vector_type(2)));
typedef float    f32x4  __attribute__((ext_vector_type(4)));

#define MFMA_F16 __builtin_amdgcn_mfma_f32_16x16x32_f16

namespace {

constexpr int M_ROWS = 64;                   // rows per block (4 waves x 64x64 tile)
// XOR-swizzled packed layouts (granule = 8 halves = 16 B):
//   Haddr(m,n) = m*256 + (((n>>3) ^ (m&7))<<3) + (n&7)     H: 32 KB (single)
//   Paddr(m,k) = PE_OFF + m*64 + (((k>>3) ^ (m&7))<<3) + (k&7) PE: 8 KB
// R16 proved 3 blocks/CU (45.5 KB LDS, (256,3)) is worth ~9%. R17 proved the
// bE/bO LDS ping-pong matters (JIT-B regressed). R18 removes R16's residual
// spill source: the cross-layer aE prefetch kept 16 regs live across the
// epilogue pressure peak (and its depth tested neutral in R12/R15). A-chunk0
// now loads at layer entry; 3-wave TLP covers the per-layer stall.
constexpr int H_OFF    = 0;                  // 16384 halves
constexpr int PE_OFF   = 16384;              // 4096 halves
constexpr int BIAS_OFF = 20480;              // 9*256 = 2304 halves
constexpr int LDS_HALVES = 22784;            // 45568 B -> 3 blocks/CU
constexpr size_t LDS_BYTES = (size_t)LDS_HALVES * sizeof(_Float16);

// Layer order: g1_0..g1_4, g2_0..g2_2, c_0, c_1, sig
constexpr int OFF_A[11] = {0,16384,81920,147456,212992,278528,360448,425984,491520,573440,577536};
constexpr int TOTAL_W   = 581632;   // fp16 elements in swizzled blob

struct Ptr11 { const float* p[11]; };

// Partial barrier: drain LDS only; register-targeted global loads stay in
// flight (consumers get per-use vmcnt waits from the compiler).
__device__ __forceinline__ void lds_barrier() {
  asm volatile("s_waitcnt lgkmcnt(0)\n\ts_barrier" ::: "memory");
}

// ---------------------------------------------------------------------------
// Weight pre-swizzle (R15): lane-fastest order -> coalesced reads. Blob:
//   256-out layers: blob[((kc*16 + nt)*64 + lane)*8 + j]
//   heads (L=9,10): blob[(kc*64 + lane)*8 + j]
//   element = W[remap(kc*32 + (lane>>4)*8 + j)][nt*16 + (lane&15)], 0 if pad.
// ---------------------------------------------------------------------------
__global__ void prep_kernel(Ptr11 wp, _Float16* __restrict__ ws) {
  int tid = blockIdx.x * blockDim.x + threadIdx.x;
  if (tid >= TOTAL_W) return;
  int L = 0;
#pragma unroll
  for (int i = 1; i < 11; ++i) if (tid >= OFF_A[i]) L = i;
  int e    = tid - OFF_A[L];
  int l15  = e & 15;           // fastest: n&15 -> coalesced W reads
  int j    = (e >> 4) & 7;
  int khi  = (e >> 7) & 3;
  int rest = e >> 9;
  int kc, nt;
  if (L <= 8) { nt = rest & 15; kc = rest >> 4; }
  else        { nt = 0;         kc = rest;      }
  int lane = khi * 16 + l15;
  int n    = nt * 16 + l15;
  int kpad = kc * 32 + khi * 8 + j;
  int k;
  if      (L == 0) k = (kpad < 63) ? kpad : -1;                               // g1_0: din 63 pad->64
  else if (L == 5) k = (kpad < 64) ? ((kpad < 63) ? kpad : -1) : kpad - 1;    // g2_0: [pe_x 63|f1 256]
  else if (L == 8) k = (kpad < 64) ? ((kpad < 39) ? kpad : -1) : kpad - 25;   // c_0:  [pe_d 39|f2 256]
  else             k = kpad;                                                  // din 256 exact
  int dout = (L == 9) ? 3 : ((L == 10) ? 1 : 256);
  float v = 0.f;
  if (k >= 0 && n < dout) v = wp.p[L][k * dout + n];
  int idx = (L <= 8) ? OFF_A[L] + ((kc * 16 + nt) * 64 + lane) * 8 + j
                     : OFF_A[L] + (kc * 64 + lane) * 8 + j;
  ws[idx] = (_Float16)v;
}

// ---------------------------------------------------------------------------
// One 256-out linear layer; wave cg computes rows [0,64) x cols [cg*64,+64).
// Single H buffer: lgkm-barrier after K-loop (reads done) and after epilogue
// (writes visible). Bias pre-loaded into acc. A: dist-1 ping-pong, chunk 0
// loaded at layer ENTRY (global load issues first; bias-init LDS reads
// overlap it; no cross-layer live range). B: bE/bO ping-pong (R17: JIT-B
// regressed). Dual-base swizzle SR (R9); all indices compile-time (R1).
// ---------------------------------------------------------------------------
template <int PE_CH, int H_CH, bool RELU>
__device__ __forceinline__ void do_layer(_Float16* lds,
                                         const _Float16* __restrict__ blob,
                                         int bias_idx, int cg, int lane) {
  constexpr int KCH = PE_CH + H_CH;   // even (2, 8, or 10)
  const int l15  = lane & 15;
  const int quad = lane >> 4;
  const int s7   = l15 & 7;          // swizzle key (row&7 == l15&7)
  const int c1   = s7 >> 2;          // chunk-granule xor bit
  const int q3   = (quad ^ (s7 & 3));

  half8 aE[4], aO[4], bE[4], bO[4];

  const _Float16* ap = blob + ((size_t)(cg * 256 + lane)) * 8;

#define LOADA(dst, KCG)                                                       \
  {                                                                           \
    const _Float16* apk = ap + (size_t)(KCG) * 8192;                          \
    _Pragma("unroll") for (int nt = 0; nt < 4; ++nt)                          \
        dst[nt] = *(const half8*)(apk + nt * 512);                            \
  }

  LOADA(aE, 0)                       // issue earliest: covers bias-init below

  // Bias -> acc init (kills the epilogue add; dead during the K-loop).
  f32x4 acc[4][4];
  {
    const _Float16* bb_ = lds + BIAS_OFF + bias_idx * 256 + cg * 64 + quad * 4;
#pragma unroll
    for (int nt = 0; nt < 4; ++nt) {
      half4v bh = *(const half4v*)(bb_ + nt * 16);
      f32x4 bf = { (float)bh[0], (float)bh[1], (float)bh[2], (float)bh[3] };
#pragma unroll
      for (int mt = 0; mt < 4; ++mt) acc[mt][nt] = bf;
    }
  }

  const _Float16* pebase = lds + PE_OFF + l15 * 64 + q3 * 8;
  const _Float16* hbase  = lds + H_OFF + l15 * 256 + q3 * 8;
  const int co = c1 << 5;            // 32-half parity correction
  const _Float16* peE = pebase + co;
  const _Float16* peO = pebase - co;
  const _Float16* hbE = hbase + co;
  const _Float16* hbO = hbase - co;

#define LOADB(bb, KCG)                                                        \
  {                                                                           \
    if ((KCG) < PE_CH) {                                                      \
      const _Float16* bpp = (((KCG) & 1) ? peO : peE) + (KCG) * 32;           \
      _Pragma("unroll") for (int mt = 0; mt < 4; ++mt)                        \
          bb[mt] = *(const half8*)(bpp + mt * 1024);                          \
    } else {                                                                  \
      const int U = (KCG) - PE_CH;                                            \
      const _Float16* bpp = ((U & 1) ? hbO : hbE) + U * 32;                   \
      _Pragma("unroll") for (int mt = 0; mt < 4; ++mt)                        \
          bb[mt] = *(const half8*)(bpp + mt * 4096);                          \
    }                                                                         \
  }

#define DO_MFMA(ab, bb)                                                       \
  {                                                                           \
    _Pragma("unroll") for (int mt = 0; mt < 4; ++mt)                          \
        _Pragma("unroll") for (int nt = 0; nt < 4; ++nt)                      \
            acc[mt][nt] = MFMA_F16(ab[nt], bb[mt], acc[mt][nt], 0, 0, 0);     \
  }

  LOADB(bE, 0)
#pragma unroll
  for (int kk = 0; kk < KCH; kk += 2) {
    LOADA(aO, kk + 1)
    LOADB(bO, kk + 1)
    DO_MFMA(aE, bE)                  // chunk kk
    if (kk + 2 < KCH) {
      LOADA(aE, kk + 2)
      LOADB(bE, kk + 2)
    }
    DO_MFMA(aO, bO)                  // chunk kk+1
  }
#undef LOADA
#undef LOADB
#undef DO_MFMA

  lds_barrier();   // all waves done READING H/PE before anyone overwrites H

  // Epilogue, SR: wa = mt*4096 + l15*256 + cg*64 + ((nt*2|qb)^s7)*8 + q1*4
  const int qb = quad >> 1, q1 = quad & 1;
  _Float16* wbase = lds + H_OFF + l15 * 256 + cg * 64 + q1 * 4;
  _Float16* wps[4] = { wbase + (((0 | qb) ^ s7) << 3),
                       wbase + (((2 | qb) ^ s7) << 3),
                       wbase + (((4 | qb) ^ s7) << 3),
                       wbase + (((6 | qb) ^ s7) << 3) };
#pragma unroll
  for (int mt = 0; mt < 4; ++mt) {
#pragma unroll
    for (int nt = 0; nt < 4; ++nt) {
      f32x4 v = acc[mt][nt];
      if (RELU) {
        v.x = fmaxf(v.x, 0.f); v.y = fmaxf(v.y, 0.f);
        v.z = fmaxf(v.z, 0.f); v.w = fmaxf(v.w, 0.f);
      }
      fp16x2v lo = __builtin_amdgcn_cvt_pkrtz(v.x, v.y);
      fp16x2v hi = __builtin_amdgcn_cvt_pkrtz(v.z, v.w);
      uint2 pk = { __builtin_bit_cast(unsigned int, lo),
                   __builtin_bit_cast(unsigned int, hi) };
      *(uint2*)(wps[nt] + mt * 4096) = pk;
    }
  }
  lds_barrier();   // writes visible to all waves
}

// Head (sig / c_1): NT=1 blob, K=256 over H; wave w rows [w*16,+16).
__device__ __forceinline__ f32x4 head_mt(const _Float16* lds,
                                         const _Float16* __restrict__ blob,
                                         int w, int lane) {
  const int l15  = lane & 15;
  const int quad = lane >> 4;
  const int s7   = l15 & 7;
  const int c1   = s7 >> 2;
  const int q3   = (quad ^ (s7 & 3));
  const _Float16* hb = lds + H_OFF + (w * 16 + l15) * 256 + q3 * 8;
  f32x4 res = (f32x4)0.f;
#pragma unroll
  for (int kc = 0; kc < 8; ++kc) {
    half8 a = *(const half8*)(blob + (kc * 64 + lane) * 8);
    half8 b = *(const half8*)(hb + ((kc ^ c1) << 5));
    res = MFMA_F16(a, b, res, 0, 0, 0);
  }
  return res;
}

// Positional encoding: f = tid&63 loop-invariant -> classify once per thread.
__device__ __forceinline__ void pe_pass(_Float16* lds, const float* __restrict__ src,
                                        int row0, int tid, int nfeat) {
  const int f  = tid & 63;
  const int rb = tid >> 6;
  const int fg = f >> 3, f7 = f & 7;
  int mode, c = 0, use_cos = 0;
  float freq = 0.f;
  if (f < 3) { mode = 0; c = f; }
  else if (f < nfeat) {
    int g = f - 3, li = g / 6, rem = g - li * 6;
    use_cos = (rem >= 3); c = use_cos ? rem - 3 : rem;
    freq = (float)(1 << li); mode = 1;
  } else mode = 2;
#pragma unroll
  for (int t = 0; t < 16; ++t) {
    int r = rb + t * 4;
    float v = 0.f;
    if (mode == 0) v = src[(row0 + r) * 3 + c];
    else if (mode == 1) {
      float a = src[(row0 + r) * 3 + c] * freq;
      v = use_cos ? __cosf(a) : __sinf(a);
    }
    lds[PE_OFF + r * 64 + (((fg ^ (r & 7)) << 3) | f7)] = (_Float16)v;
  }
}

__global__ __launch_bounds__(256, 3) void nerf_kernel(
    const _Float16* __restrict__ ws, const float* __restrict__ x,
    const float* __restrict__ dirp, Ptr11 bp, float* __restrict__ out) {
  extern __shared__ _Float16 lds[];
  const int tid  = threadIdx.x;
  const int lane = tid & 63;
  const int w    = tid >> 6;       // wave 0..3 (= col-group cg)
  const int l15  = lane & 15;
  const int quad = lane >> 4;
  const int row0 = blockIdx.x * M_ROWS;

  // ---- pe_x -> PE buffer; biases -> LDS (f16, once) ----
  pe_pass(lds, x, row0, tid, 63);
#pragma unroll
  for (int L = 0; L < 9; ++L)
    lds[BIAS_OFF + L * 256 + tid] = (_Float16)bp.p[L][tid];
  lds_barrier();

  // ---- G1: 63->256, 256->256 x4 (ReLU on all but last) ----
  do_layer<2, 0, true >(lds, ws + OFF_A[0], 0, w, lane);
  do_layer<0, 8, true >(lds, ws + OFF_A[1], 1, w, lane);
  do_layer<0, 8, true >(lds, ws + OFF_A[2], 2, w, lane);
  do_layer<0, 8, true >(lds, ws + OFF_A[3], 3, w, lane);
  do_layer<0, 8, false>(lds, ws + OFF_A[4], 4, w, lane);  // f1
  // ---- G2: [pe_x|f1] -> 256, 256->256, 256->256 (no ReLU on last) ----
  do_layer<2, 8, true >(lds, ws + OFF_A[5], 5, w, lane);  // pe_x last use
  do_layer<0, 8, true >(lds, ws + OFF_A[6], 6, w, lane);
  do_layer<0, 8, false>(lds, ws + OFF_A[7], 7, w, lane);  // f2

  // ---- sigma head reads f2; pe_d overwrites PE (pe_x dead) ----
  f32x4 sa = head_mt(lds, ws + OFF_A[10], w, lane);
  float sigv = sa[0] + bp.p[10][0];   // valid in quad==0 lanes
  pe_pass(lds, dirp, row0, tid, 39);
  lds_barrier();     // pe_d visible before c_0; sig H-reads done

  // ---- color: c_0 [pe_d|f2] -> H (ReLU), c_1 reads H ----
  do_layer<2, 8, true>(lds, ws + OFF_A[8], 8, w, lane);
  f32x4 ca = head_mt(lds, ws + OFF_A[9], w, lane);
  if (quad == 0) {
    f32x4 o = { ca[0] + bp.p[9][0], ca[1] + bp.p[9][1], ca[2] + bp.p[9][2], sigv };
    *(f32x4*)(out + (size_t)(row0 + w * 16 + l15) * 4) = o;
  }
}

}  // namespace

extern "C" void kernel_launch(void* const* d_in, const int* in_sizes, int n_in,
                              void* d_out, int out_size, void* d_ws, size_t ws_size,
                              hipStream_t stream) {
  const float* x   = (const float*)d_in[0];
  const float* dir = (const float*)d_in[1];
  Ptr11 wp, bp;
  for (int i = 0; i < 11; ++i) {
    wp.p[i] = (const float*)d_in[2 + 2 * i];
    bp.p[i] = (const float*)d_in[3 + 2 * i];
  }
  _Float16* ws = (_Float16*)d_ws;
  float* out = (float*)d_out;

  (void)hipFuncSetAttribute((const void*)nerf_kernel,
                            hipFuncAttributeMaxDynamicSharedMemorySize,
                            (int)LDS_BYTES);

  prep_kernel<<<(TOTAL_W + 255) / 256, 256, 0, stream>>>(wp, ws);
  nerf_kernel<<<262144 / M_ROWS, 256, LDS_BYTES, stream>>>(ws, x, dir, bp, out);
}